// Round 1
// 1154.142 us; speedup vs baseline: 1.3155x; 1.3155x over previous
//
#include <hip/hip_runtime.h>
#include <cstddef>
#include <cstdint>

#define PI_F    3.14159265358979323846f
#define TWOPI_F 6.28318530717958647692f

// B=8, C=64, H=256, W=512, WF=64, RANK=32, N=H*W=131072
// d_out (67,108,864 floats) doubles as scratch:
//   Zw/Zc: [0, 16777216)   Zh: [16777216, 33554432)   G: [33554432, 33816576)
//   TW (bf16 twiddle tables): [33816576, 34078720)
#define ZH_OFF 16777216u
#define G_OFF  33554432u
#define TW_OFF 33816576u

typedef __attribute__((ext_vector_type(8))) short bf16x8;
typedef __attribute__((ext_vector_type(4))) float f32x4;

// round-to-nearest-even fp32 -> bf16 hi/lo split: x ~= hi + lo, err ~ 2^-17 |x|
__device__ __forceinline__ void bsplit(float x, short& h, short& l) {
    uint32_t u  = __float_as_uint(x);
    uint32_t hb = (u + 0x7fffu + ((u >> 16) & 1u)) & 0xffff0000u;
    h = (short)(hb >> 16);
    float r = x - __uint_as_float(hb);
    uint32_t u2 = __float_as_uint(r);
    l = (short)((u2 + 0x7fffu + ((u2 >> 16) & 1u)) >> 16);
}

// ---------------- filter: pool -> params -> softplus/tanh -> rank-sum -> G = filt-1 ----------------
__global__ __launch_bounds__(256) void k_filt(const float* __restrict__ x,
                                              const float* __restrict__ dt,
                                              const float* __restrict__ wmat,
                                              const float* __restrict__ bvec,
                                              float* __restrict__ G) {
    __shared__ float pooled[64 * 65];
    __shared__ float wsh[64 * 65];
    int t = threadIdx.x;
    int b = blockIdx.x >> 8, h = blockIdx.x & 255;
    for (int i = t; i < 4096; i += 256)
        wsh[(i >> 6) * 65 + (i & 63)] = wmat[i];
    for (int c = 0; c < 64; c++) {
        const float* xr = x + (((size_t)(b * 64 + c)) * 256 + h) * 512;
        float2 v = ((const float2*)xr)[t];
        float s = v.x + v.y;
        s += __shfl_xor(s, 1);
        s += __shfl_xor(s, 2);
        if ((t & 3) == 0) pooled[c * 65 + (t >> 2)] = s * 0.125f;
    }
    __syncthreads();
    float dtb = dt[b];
    int o = t & 63, q = t >> 6;
    float bo = bvec[o];
    for (int jj = 0; jj < 16; jj++) {
        int j = q * 16 + jj;
        float acc = bo;
        #pragma unroll 16
        for (int c = 0; c < 64; c++)
            acc = fmaf(wsh[o * 65 + c], pooled[c * 65 + j], acc);
        float nl;
        if (o < 32) nl = (acc > 20.0f) ? acc : log1pf(expf(acc));   // softplus -> nu
        else        nl = tanhf(acc) * PI_F;                          // theta
        float other = __shfl_xor(nl, 32);
        float nu = (o < 32) ? nl : other;
        float th = (o < 32) ? other : nl;
        float decay = expf(-nu * dtb);
        float sa, ca; sincosf(th * dtb, &sa, &ca);
        float tr = decay * ca, ti = decay * sa;
        #pragma unroll
        for (int off = 1; off < 64; off <<= 1) {
            tr += __shfl_xor(tr, off);
            ti += __shfl_xor(ti, off);
        }
        if ((t & 63) == 0) {
            float2 g = make_float2(0.5f * tr - 1.0f, 0.5f * ti);   // filt - 1
            ((float2*)G)[((size_t)b * 256 + h) * 64 + j] = g;
        }
    }
}

// ---------------- A: Zw[r][2wf+ri] = sum_w x[r][w] * e^{-2pi i w wf/512}, twiddles on-the-fly ----------------
__global__ __launch_bounds__(256) void k_gemmA(const float* __restrict__ x,
                                               float* __restrict__ Zw) {
    __shared__ __align__(16) float As[32][68];
    __shared__ __align__(16) float Bs[32][64];
    int t = threadIdx.x;
    int row0 = blockIdx.x * 64, n0 = blockIdx.y * 64;
    int lr = t >> 3, lk4 = (t & 7) << 2;
    int bkr = t >> 4, bc4 = (t & 15) << 2;
    int ty = t >> 4, tx = t & 15;
    int wf0 = (n0 + bc4) >> 1;
    float u_r[2], u_i[2], c16r[2], c16i[2], advr[2], advi[2];
    #pragma unroll
    for (int q = 0; q < 2; q++) {
        int wf = wf0 + q;
        float s, c;
        sincosf((float)((bkr * wf) & 511) * (TWOPI_F / 512.0f), &s, &c);
        u_r[q] = c; u_i[q] = -s;
        sincosf((float)((16 * wf) & 511) * (TWOPI_F / 512.0f), &s, &c);
        c16r[q] = c; c16i[q] = -s;
        sincosf((float)((32 * wf) & 511) * (TWOPI_F / 512.0f), &s, &c);
        advr[q] = c; advi[q] = -s;
    }
    float acc[4][4] = {};
    size_t xrow0 = (size_t)(row0 + lr) * 512;
    size_t xrow1 = (size_t)(row0 + lr + 32) * 512;
    for (int k0 = 0; k0 < 512; k0 += 32) {
        __syncthreads();
        {
            float4 v = *(const float4*)(x + xrow0 + k0 + lk4);
            As[lk4 + 0][lr] = v.x; As[lk4 + 1][lr] = v.y;
            As[lk4 + 2][lr] = v.z; As[lk4 + 3][lr] = v.w;
        }
        {
            float4 v = *(const float4*)(x + xrow1 + k0 + lk4);
            int m = lr + 32;
            As[lk4 + 0][m] = v.x; As[lk4 + 1][m] = v.y;
            As[lk4 + 2][m] = v.z; As[lk4 + 3][m] = v.w;
        }
        *(float4*)&Bs[bkr][bc4] = make_float4(u_r[0], u_i[0], u_r[1], u_i[1]);
        {
            float r0 = u_r[0] * c16r[0] - u_i[0] * c16i[0];
            float i0 = u_r[0] * c16i[0] + u_i[0] * c16r[0];
            float r1 = u_r[1] * c16r[1] - u_i[1] * c16i[1];
            float i1 = u_r[1] * c16i[1] + u_i[1] * c16r[1];
            *(float4*)&Bs[bkr + 16][bc4] = make_float4(r0, i0, r1, i1);
        }
        #pragma unroll
        for (int q = 0; q < 2; q++) {
            float nr = u_r[q] * advr[q] - u_i[q] * advi[q];
            float ni = u_r[q] * advi[q] + u_i[q] * advr[q];
            u_r[q] = nr; u_i[q] = ni;
        }
        __syncthreads();
        #pragma unroll
        for (int kk = 0; kk < 32; kk++) {
            float4 ra = *(const float4*)&As[kk][ty << 2];
            float4 rb = *(const float4*)&Bs[kk][tx << 2];
            float a[4] = {ra.x, ra.y, ra.z, ra.w};
            float bq[4] = {rb.x, rb.y, rb.z, rb.w};
            #pragma unroll
            for (int i = 0; i < 4; i++)
                #pragma unroll
                for (int j = 0; j < 4; j++)
                    acc[i][j] = fmaf(a[i], bq[j], acc[i][j]);
        }
    }
    #pragma unroll
    for (int i = 0; i < 4; i++) {
        int r = row0 + (ty << 2) + i;
        *(float4*)(Zw + (size_t)r * 128 + n0 + (tx << 2)) =
            make_float4(acc[i][0], acc[i][1], acc[i][2], acc[i][3]);
    }
}

// ---------------- twiddle tables: [4][256m][256k] bf16 per direction (Trh,Trl,Tih,Til) ----------------
// fwd: T = e^{-2pi i mk/256} -> Ti = -sin ;  inv: Ti = +sin
__global__ __launch_bounds__(256) void k_twid(float* __restrict__ outbase) {
    int t = blockIdx.x * 256 + threadIdx.x;   // t = m*256 + k
    int m = t >> 8, k = t & 255;
    float s, c;
    sincosf((float)((m * k) & 255) * (TWOPI_F / 256.0f), &s, &c);
    short ch, cl, nsh, nsl, psh, psl;
    bsplit(c, ch, cl);
    bsplit(-s, nsh, nsl);
    bsplit(s, psh, psl);
    short* fw = (short*)(outbase + TW_OFF);
    short* iv = fw + 262144;
    fw[t] = ch; fw[65536 + t] = cl; fw[131072 + t] = nsh; fw[196608 + t] = nsl;
    iv[t] = ch; iv[65536 + t] = cl; iv[131072 + t] = psh; iv[196608 + t] = psl;
}

// ---------------- B/D as bf16 MFMA with hi/lo split (3 cross terms ~ fp32 precision) --------------
// Zout[m][j] = sum_k T[m][k] * Zin[k][j]  (complex, per plane); optional *G epilogue (fwd only).
// A = T staged from precomputed tables; B = Z staged fp32->hi/lo, transposed to [j][k].
__global__ __launch_bounds__(256) void k_cgemm_mfma(const float* __restrict__ Zin,
                                                    float* __restrict__ Zout,
                                                    const float* __restrict__ G,
                                                    const short* __restrict__ tab) {
    __shared__ short As[4][64][40];   // Trh,Trl,Tih,Til  [m][k] (stride 40 -> 80B rows)
    __shared__ short Bs[4][64][40];   // Zrh,Zrl,Zih,Zil  [j][k]
    int t = threadIdx.x;
    int p  = blockIdx.x;              // plane (b*64+c)
    int m0 = blockIdx.y * 64;         // output-row tile
    size_t zbase = (size_t)p * 32768;
    int w = t >> 6, l = t & 63;
    int wm = w >> 1, wj = w & 1;      // 2x2 wave grid: 32m x 32j per wave
    int lr = l & 15, lh = l >> 4;     // frag row/col, k-group
    int att = w;                      // A-stage: one type per wave
    int bk  = t >> 3;                 // B-stage k row 0..31
    int bju = t & 7;                  //          j pair unit

    f32x4 accRp[2][2] = {}, accRm[2][2] = {}, accI[2][2] = {};

    #pragma unroll 1
    for (int k0 = 0; k0 < 256; k0 += 32) {
        __syncthreads();
        {   // stage A: wave 'att' loads its table slice: 64 rows x 32k bf16
            const short* tb = tab + att * 65536 + k0;
            #pragma unroll
            for (int i = 0; i < 4; i++) {
                int c = l + 64 * i;
                int row = c >> 2, ko = (c & 3) << 3;
                int4 v = *(const int4*)(tb + (m0 + row) * 256 + ko);
                *(int4*)&As[att][row][ko] = v;
            }
        }
        // stage B: read Z (k-major complex), split, transpose to [j][k]
        #pragma unroll
        for (int pass = 0; pass < 4; pass++) {
            int j = 2 * bju + 16 * pass;
            float4 v = *(const float4*)(Zin + zbase + (size_t)(k0 + bk) * 128 + j * 2);
            short h0, l0, h1, l1;
            bsplit(v.x, h0, l0); bsplit(v.y, h1, l1);
            Bs[0][j][bk] = h0; Bs[1][j][bk] = l0; Bs[2][j][bk] = h1; Bs[3][j][bk] = l1;
            bsplit(v.z, h0, l0); bsplit(v.w, h1, l1);
            Bs[0][j + 1][bk] = h0; Bs[1][j + 1][bk] = l0; Bs[2][j + 1][bk] = h1; Bs[3][j + 1][bk] = l1;
        }
        __syncthreads();
        // fragment loads (A: row=lane&15, k=8*(lane>>4)+i ; B: col=lane&15, same k)
        bf16x8 trh[2], trl[2], tih[2], til[2], zrh[2], zrl[2], zih[2], zil[2];
        #pragma unroll
        for (int s = 0; s < 2; s++) {
            int ar = wm * 32 + s * 16 + lr;
            trh[s] = *(const bf16x8*)&As[0][ar][lh << 3];
            trl[s] = *(const bf16x8*)&As[1][ar][lh << 3];
            tih[s] = *(const bf16x8*)&As[2][ar][lh << 3];
            til[s] = *(const bf16x8*)&As[3][ar][lh << 3];
            int br = wj * 32 + s * 16 + lr;
            zrh[s] = *(const bf16x8*)&Bs[0][br][lh << 3];
            zrl[s] = *(const bf16x8*)&Bs[1][br][lh << 3];
            zih[s] = *(const bf16x8*)&Bs[2][br][lh << 3];
            zil[s] = *(const bf16x8*)&Bs[3][br][lh << 3];
        }
        #pragma unroll
        for (int i = 0; i < 2; i++)
            #pragma unroll
            for (int jj = 0; jj < 2; jj++) {
                // Re+ : Tr*Zr
                accRp[i][jj] = __builtin_amdgcn_mfma_f32_16x16x32_bf16(trh[i], zrh[jj], accRp[i][jj], 0, 0, 0);
                accRp[i][jj] = __builtin_amdgcn_mfma_f32_16x16x32_bf16(trh[i], zrl[jj], accRp[i][jj], 0, 0, 0);
                accRp[i][jj] = __builtin_amdgcn_mfma_f32_16x16x32_bf16(trl[i], zrh[jj], accRp[i][jj], 0, 0, 0);
                // Re- : Ti*Zi (subtracted in epilogue)
                accRm[i][jj] = __builtin_amdgcn_mfma_f32_16x16x32_bf16(tih[i], zih[jj], accRm[i][jj], 0, 0, 0);
                accRm[i][jj] = __builtin_amdgcn_mfma_f32_16x16x32_bf16(tih[i], zil[jj], accRm[i][jj], 0, 0, 0);
                accRm[i][jj] = __builtin_amdgcn_mfma_f32_16x16x32_bf16(til[i], zih[jj], accRm[i][jj], 0, 0, 0);
                // Im : Tr*Zi + Ti*Zr
                accI[i][jj]  = __builtin_amdgcn_mfma_f32_16x16x32_bf16(trh[i], zih[jj], accI[i][jj], 0, 0, 0);
                accI[i][jj]  = __builtin_amdgcn_mfma_f32_16x16x32_bf16(trh[i], zil[jj], accI[i][jj], 0, 0, 0);
                accI[i][jj]  = __builtin_amdgcn_mfma_f32_16x16x32_bf16(trl[i], zih[jj], accI[i][jj], 0, 0, 0);
                accI[i][jj]  = __builtin_amdgcn_mfma_f32_16x16x32_bf16(tih[i], zrh[jj], accI[i][jj], 0, 0, 0);
                accI[i][jj]  = __builtin_amdgcn_mfma_f32_16x16x32_bf16(tih[i], zrl[jj], accI[i][jj], 0, 0, 0);
                accI[i][jj]  = __builtin_amdgcn_mfma_f32_16x16x32_bf16(til[i], zrh[jj], accI[i][jj], 0, 0, 0);
            }
    }
    // epilogue: C/D layout col=lane&15, row=4*(lane>>4)+reg (m89-verified)
    int b = p >> 6;
    #pragma unroll
    for (int i = 0; i < 2; i++)
        #pragma unroll
        for (int jj = 0; jj < 2; jj++) {
            int jcol = wj * 32 + jj * 16 + lr;
            #pragma unroll
            for (int r = 0; r < 4; r++) {
                int m = m0 + wm * 32 + i * 16 + (lh << 2) + r;
                float re = accRp[i][jj][r] - accRm[i][jj][r];
                float im = accI[i][jj][r];
                if (G) {
                    float2 g = ((const float2*)G)[((size_t)b * 256 + m) * 64 + jcol];
                    float nr = re * g.x - im * g.y;
                    float ni = re * g.y + im * g.x;
                    re = nr; im = ni;
                }
                ((float2*)(Zout + zbase))[(size_t)m * 64 + jcol] = make_float2(re, im);
            }
        }
}

// ---------------- E: out = x + Zc (rows x 128) * S (128 x 512), S on-the-fly ----------------
__global__ __launch_bounds__(256) void k_gemmE(const float* __restrict__ Zc,
                                               const float* __restrict__ x,
                                               float* __restrict__ out,
                                               int rowLo) {
    __shared__ __align__(16) float As[32][68];
    __shared__ __align__(16) float Bs[32][64];
    int t = threadIdx.x;
    int row0 = rowLo + blockIdx.x * 64, n0 = blockIdx.y * 64;
    int lr = t >> 3, lk4 = (t & 7) << 2;
    int bkr = t >> 4, bc4 = (t & 15) << 2;
    int ty = t >> 4, tx = t & 15;
    const float invN = 1.0f / 131072.0f;
    int par = bkr & 1;
    int wfh = bkr >> 1;
    float u_r[4], u_i[4], c8r[4], c8i[4], advr[4], advi[4];
    #pragma unroll
    for (int d = 0; d < 4; d++) {
        int w = n0 + bc4 + d;
        float s, c;
        sincosf((float)((w * wfh) & 511) * (TWOPI_F / 512.0f), &s, &c);
        u_r[d] = c; u_i[d] = -s;
        sincosf((float)((w * 8) & 511) * (TWOPI_F / 512.0f), &s, &c);
        c8r[d] = c; c8i[d] = -s;
        sincosf((float)((w * 16) & 511) * (TWOPI_F / 512.0f), &s, &c);
        advr[d] = c; advi[d] = -s;
    }
    float acc[4][4] = {};
    for (int k0 = 0; k0 < 128; k0 += 32) {
        __syncthreads();
        {
            float4 v = *(const float4*)(Zc + (size_t)(row0 + lr) * 128 + k0 + lk4);
            As[lk4 + 0][lr] = v.x; As[lk4 + 1][lr] = v.y;
            As[lk4 + 2][lr] = v.z; As[lk4 + 3][lr] = v.w;
        }
        {
            float4 v = *(const float4*)(Zc + (size_t)(row0 + lr + 32) * 128 + k0 + lk4);
            int mm = lr + 32;
            As[lk4 + 0][mm] = v.x; As[lk4 + 1][mm] = v.y;
            As[lk4 + 2][mm] = v.z; As[lk4 + 3][mm] = v.w;
        }
        int wf1 = (k0 >> 1) + wfh;
        float a1 = ((wf1 == 0) ? 1.0f : 2.0f) * invN;
        float a2 = 2.0f * invN;
        float b1[4], b2[4];
        #pragma unroll
        for (int d = 0; d < 4; d++) {
            b1[d] = a1 * (par ? u_i[d] : u_r[d]);
            float vr = u_r[d] * c8r[d] - u_i[d] * c8i[d];
            float vi = u_r[d] * c8i[d] + u_i[d] * c8r[d];
            b2[d] = a2 * (par ? vi : vr);
            float nr = u_r[d] * advr[d] - u_i[d] * advi[d];
            float ni = u_r[d] * advi[d] + u_i[d] * advr[d];
            u_r[d] = nr; u_i[d] = ni;
        }
        *(float4*)&Bs[bkr][bc4]      = make_float4(b1[0], b1[1], b1[2], b1[3]);
        *(float4*)&Bs[bkr + 16][bc4] = make_float4(b2[0], b2[1], b2[2], b2[3]);
        __syncthreads();
        #pragma unroll
        for (int kk = 0; kk < 32; kk++) {
            float4 ra = *(const float4*)&As[kk][ty << 2];
            float4 rb = *(const float4*)&Bs[kk][tx << 2];
            float a[4] = {ra.x, ra.y, ra.z, ra.w};
            float bq[4] = {rb.x, rb.y, rb.z, rb.w};
            #pragma unroll
            for (int i = 0; i < 4; i++)
                #pragma unroll
                for (int j = 0; j < 4; j++)
                    acc[i][j] = fmaf(a[i], bq[j], acc[i][j]);
        }
    }
    #pragma unroll
    for (int i = 0; i < 4; i++) {
        int r = row0 + (ty << 2) + i;
        size_t grow = (size_t)r * 512;
        float4 xv = *(const float4*)(x + grow + n0 + (tx << 2));
        *(float4*)(out + grow + n0 + (tx << 2)) =
            make_float4(acc[i][0] + xv.x, acc[i][1] + xv.y,
                        acc[i][2] + xv.z, acc[i][3] + xv.w);
    }
}

// ---------------- stage Zc planes 0..1 (65536 floats) into ws ----------------
__global__ __launch_bounds__(256) void k_copy(const float* __restrict__ src,
                                              float* __restrict__ dst) {
    int i = blockIdx.x * 256 + threadIdx.x;
    ((float4*)dst)[i] = ((const float4*)src)[i];
}

extern "C" void kernel_launch(void* const* d_in, const int* in_sizes, int n_in,
                              void* d_out, int out_size, void* d_ws, size_t ws_size,
                              hipStream_t stream) {
    (void)in_sizes; (void)n_in; (void)out_size; (void)ws_size;
    const float* x    = (const float*)d_in[0];
    const float* dt   = (const float*)d_in[1];
    const float* wmat = (const float*)d_in[2];
    const float* bvec = (const float*)d_in[3];
    float* out = (float*)d_out;
    float* ws  = (float*)d_ws;

    float* G   = out + G_OFF;     // [33.55M, 33.82M) floats of d_out
    float* Zw  = out;             // [0, 16.77M)
    float* Zh  = out + ZH_OFF;    // [16.77M, 33.55M)
    float* Zc  = out;             // reuses Zw region
    float* stg = ws;              // 65536 floats = 256 KB
    const short* tabF = (const short*)(out + TW_OFF);   // fwd tables (4 x 256 x 256 bf16)
    const short* tabI = tabF + 262144;                  // inv tables

    k_filt <<<2048,            256, 0, stream>>>(x, dt, wmat, bvec, G);
    k_twid <<<256,             256, 0, stream>>>(out);
    k_gemmA<<<dim3(2048, 2),   256, 0, stream>>>(x, Zw);
    k_cgemm_mfma<<<dim3(512, 4), 256, 0, stream>>>(Zw, Zh, G, tabF);      // fwd h-DFT + filter
    k_cgemm_mfma<<<dim3(512, 4), 256, 0, stream>>>(Zh, Zc, nullptr, tabI); // inv h-DFT
    k_copy <<<64,              256, 0, stream>>>(Zc, stg);
    // Descending-plane cascade: out plane p clobbers Zc planes 4p..4p+3,
    // which are only read by strictly earlier launches.
    k_gemmE<<<dim3(1536, 8),   256, 0, stream>>>(Zc,  x, out, 128 * 256); // planes 128..511
    k_gemmE<<<dim3(384, 8),    256, 0, stream>>>(Zc,  x, out, 32 * 256);  // planes 32..127
    k_gemmE<<<dim3(96, 8),     256, 0, stream>>>(Zc,  x, out, 8 * 256);   // planes 8..31
    k_gemmE<<<dim3(24, 8),     256, 0, stream>>>(Zc,  x, out, 2 * 256);   // planes 2..7
    k_gemmE<<<dim3(8, 8),      256, 0, stream>>>(stg, x, out, 0);         // planes 0..1 (staged)
}

// Round 2
// 1013.284 us; speedup vs baseline: 1.4984x; 1.1390x over previous
//
#include <hip/hip_runtime.h>
#include <cstddef>
#include <cstdint>

#define PI_F    3.14159265358979323846f
#define TWOPI_F 6.28318530717958647692f

// B=8, C=64, H=256, W=512, WF=64, RANK=32, N=H*W=131072
// d_out (67,108,864 floats) doubles as scratch:
//   Zw/Zc: [0, 16777216)   Zh: [16777216, 33554432)   G: [33554432, 33816576)
//   TW (bf16 twiddle tables, cgemm): [33816576, 34078720)
//   TWA (bf16 W-DFT table, gemmA):   [34078720, 34144256)
#define ZH_OFF  16777216u
#define G_OFF   33554432u
#define TW_OFF  33816576u
#define TWA_OFF 34078720u

typedef __attribute__((ext_vector_type(8))) short bf16x8;
typedef __attribute__((ext_vector_type(4))) short s16x4;
typedef __attribute__((ext_vector_type(4))) float f32x4;

// round-to-nearest-even fp32 -> bf16 hi/lo split: x ~= hi + lo, err ~ 2^-17 |x|
__device__ __forceinline__ void bsplit(float x, short& h, short& l) {
    uint32_t u  = __float_as_uint(x);
    uint32_t hb = (u + 0x7fffu + ((u >> 16) & 1u)) & 0xffff0000u;
    h = (short)(hb >> 16);
    float r = x - __uint_as_float(hb);
    uint32_t u2 = __float_as_uint(r);
    l = (short)((u2 + 0x7fffu + ((u2 >> 16) & 1u)) >> 16);
}

// ---------------- filter: pool -> params -> softplus/tanh -> rank-sum -> G = filt-1 ----------------
__global__ __launch_bounds__(256) void k_filt(const float* __restrict__ x,
                                              const float* __restrict__ dt,
                                              const float* __restrict__ wmat,
                                              const float* __restrict__ bvec,
                                              float* __restrict__ G) {
    __shared__ float pooled[64 * 65];
    __shared__ float wsh[64 * 65];
    int t = threadIdx.x;
    int b = blockIdx.x >> 8, h = blockIdx.x & 255;
    for (int i = t; i < 4096; i += 256)
        wsh[(i >> 6) * 65 + (i & 63)] = wmat[i];
    for (int c = 0; c < 64; c++) {
        const float* xr = x + (((size_t)(b * 64 + c)) * 256 + h) * 512;
        float2 v = ((const float2*)xr)[t];
        float s = v.x + v.y;
        s += __shfl_xor(s, 1);
        s += __shfl_xor(s, 2);
        if ((t & 3) == 0) pooled[c * 65 + (t >> 2)] = s * 0.125f;
    }
    __syncthreads();
    float dtb = dt[b];
    int o = t & 63, q = t >> 6;
    float bo = bvec[o];
    for (int jj = 0; jj < 16; jj++) {
        int j = q * 16 + jj;
        float acc = bo;
        #pragma unroll 16
        for (int c = 0; c < 64; c++)
            acc = fmaf(wsh[o * 65 + c], pooled[c * 65 + j], acc);
        float nl;
        if (o < 32) nl = (acc > 20.0f) ? acc : log1pf(expf(acc));   // softplus -> nu
        else        nl = tanhf(acc) * PI_F;                          // theta
        float other = __shfl_xor(nl, 32);
        float nu = (o < 32) ? nl : other;
        float th = (o < 32) ? other : nl;
        float decay = expf(-nu * dtb);
        float sa, ca; sincosf(th * dtb, &sa, &ca);
        float tr = decay * ca, ti = decay * sa;
        #pragma unroll
        for (int off = 1; off < 64; off <<= 1) {
            tr += __shfl_xor(tr, off);
            ti += __shfl_xor(ti, off);
        }
        if ((t & 63) == 0) {
            float2 g = make_float2(0.5f * tr - 1.0f, 0.5f * ti);   // filt - 1
            ((float2*)G)[((size_t)b * 256 + h) * 64 + j] = g;
        }
    }
}

// ---------------- twiddle tables for cgemm: [4][256m][256k] bf16 per direction ----------------
__global__ __launch_bounds__(256) void k_twid(float* __restrict__ outbase) {
    int t = blockIdx.x * 256 + threadIdx.x;   // t = m*256 + k
    int m = t >> 8, k = t & 255;
    float s, c;
    sincosf((float)((m * k) & 255) * (TWOPI_F / 256.0f), &s, &c);
    short ch, cl, nsh, nsl, psh, psl;
    bsplit(c, ch, cl);
    bsplit(-s, nsh, nsl);
    bsplit(s, psh, psl);
    short* fw = (short*)(outbase + TW_OFF);
    short* iv = fw + 262144;
    fw[t] = ch; fw[65536 + t] = cl; fw[131072 + t] = nsh; fw[196608 + t] = nsl;
    iv[t] = ch; iv[65536 + t] = cl; iv[131072 + t] = psh; iv[196608 + t] = psl;
}

// ---------------- W-DFT table for gemmA: [2(hi/lo)][128 n][512 w] bf16 ----------------
// col n = 2*wf+ri:  ri=0 -> cos(2pi w wf/512),  ri=1 -> -sin(2pi w wf/512)
__global__ __launch_bounds__(256) void k_twidA(float* __restrict__ outbase) {
    int t = blockIdx.x * 256 + threadIdx.x;   // 0..65535 = n*512 + w
    int n = t >> 9, ww = t & 511;
    int wf = n >> 1;
    float s, c;
    sincosf((float)((ww * wf) & 511) * (TWOPI_F / 512.0f), &s, &c);
    float val = (n & 1) ? -s : c;
    short h, lo; bsplit(val, h, lo);
    short* ta = (short*)(outbase + TWA_OFF);
    ta[t] = h;            // hi plane
    ta[65536 + t] = lo;   // lo plane
}

// ---------------- A as bf16 MFMA: Zw[r][n] = sum_w x[r][w] * T[n][w], hi/lo split ----------------
// Block: 64 rows x 128 cols (full N), 4 waves 2x2 (32m x 64n each), K=512 in steps of 32.
__global__ __launch_bounds__(256) void k_gemmA_mfma(const float* __restrict__ x,
                                                    float* __restrict__ Zw,
                                                    const short* __restrict__ tabA) {
    __shared__ short As[2][64][40];    // x hi/lo   [m][k]
    __shared__ short Bs[2][128][40];   // T hi/lo   [n][k]
    int t = threadIdx.x;
    int row0 = blockIdx.x * 64;
    int w = t >> 6, l = t & 63;
    int wm = w >> 1, wj = w & 1;
    int lr = l & 15, lh = l >> 4;
    f32x4 acc[2][4] = {};
    #pragma unroll 1
    for (int k0 = 0; k0 < 512; k0 += 32) {
        __syncthreads();
        // stage A: 64 rows x 32 k fp32 -> hi/lo bf16
        #pragma unroll
        for (int rep = 0; rep < 2; rep++) {
            int f = t + 256 * rep;               // 0..511
            int r = f >> 3, c4 = (f & 7) << 2;
            float4 v = *(const float4*)(x + (size_t)(row0 + r) * 512 + k0 + c4);
            s16x4 hv, lv;
            short h, lo;
            bsplit(v.x, h, lo); hv.x = h; lv.x = lo;
            bsplit(v.y, h, lo); hv.y = h; lv.y = lo;
            bsplit(v.z, h, lo); hv.z = h; lv.z = lo;
            bsplit(v.w, h, lo); hv.w = h; lv.w = lo;
            *(s16x4*)&As[0][r][c4] = hv;
            *(s16x4*)&As[1][r][c4] = lv;
        }
        // stage B from table: 2 comps x 128 n x 32 k (bf16, L2-resident)
        {
            int comp = t >> 7, u = t & 127;
            const short* tb = tabA + comp * 65536 + k0;
            #pragma unroll
            for (int q = 0; q < 4; q++) {
                int f = u * 4 + q;               // 0..511 per comp
                int n = f >> 2, ko = (f & 3) << 3;
                int4 v = *(const int4*)(tb + n * 512 + ko);
                *(int4*)&Bs[comp][n][ko] = v;
            }
        }
        __syncthreads();
        // fragments (A: row=lane&15, k=8*(lane>>4)+i ; B: col=lane&15, same k)
        bf16x8 ah[2], al[2], bh[4], bl[4];
        #pragma unroll
        for (int s = 0; s < 2; s++) {
            int ar = wm * 32 + s * 16 + lr;
            ah[s] = *(const bf16x8*)&As[0][ar][lh << 3];
            al[s] = *(const bf16x8*)&As[1][ar][lh << 3];
        }
        #pragma unroll
        for (int j = 0; j < 4; j++) {
            int bn = wj * 64 + j * 16 + lr;
            bh[j] = *(const bf16x8*)&Bs[0][bn][lh << 3];
            bl[j] = *(const bf16x8*)&Bs[1][bn][lh << 3];
        }
        #pragma unroll
        for (int s = 0; s < 2; s++)
            #pragma unroll
            for (int j = 0; j < 4; j++) {
                acc[s][j] = __builtin_amdgcn_mfma_f32_16x16x32_bf16(ah[s], bh[j], acc[s][j], 0, 0, 0);
                acc[s][j] = __builtin_amdgcn_mfma_f32_16x16x32_bf16(ah[s], bl[j], acc[s][j], 0, 0, 0);
                acc[s][j] = __builtin_amdgcn_mfma_f32_16x16x32_bf16(al[s], bh[j], acc[s][j], 0, 0, 0);
            }
    }
    // epilogue: C/D col=lane&15, row=4*(lane>>4)+reg (m89-verified)
    #pragma unroll
    for (int s = 0; s < 2; s++)
        #pragma unroll
        for (int j = 0; j < 4; j++) {
            int col = wj * 64 + j * 16 + lr;
            #pragma unroll
            for (int r4 = 0; r4 < 4; r4++) {
                int r = row0 + wm * 32 + s * 16 + (lh << 2) + r4;
                Zw[(size_t)r * 128 + col] = acc[s][j][r4];
            }
        }
}

// ---------------- B/D as bf16 MFMA with hi/lo split (3 cross terms ~ fp32 precision) --------------
__global__ __launch_bounds__(256) void k_cgemm_mfma(const float* __restrict__ Zin,
                                                    float* __restrict__ Zout,
                                                    const float* __restrict__ G,
                                                    const short* __restrict__ tab) {
    __shared__ short As[4][64][40];   // Trh,Trl,Tih,Til  [m][k]
    __shared__ short Bs[4][64][40];   // Zrh,Zrl,Zih,Zil  [j][k]
    int t = threadIdx.x;
    int p  = blockIdx.x;              // plane (b*64+c)
    int m0 = blockIdx.y * 64;         // output-row tile
    size_t zbase = (size_t)p * 32768;
    int w = t >> 6, l = t & 63;
    int wm = w >> 1, wj = w & 1;      // 2x2 wave grid: 32m x 32j per wave
    int lr = l & 15, lh = l >> 4;
    int att = w;
    int bk  = t >> 3;
    int bju = t & 7;

    f32x4 accRp[2][2] = {}, accRm[2][2] = {}, accI[2][2] = {};

    #pragma unroll 1
    for (int k0 = 0; k0 < 256; k0 += 32) {
        __syncthreads();
        {   // stage A: wave 'att' loads its table slice: 64 rows x 32k bf16
            const short* tb = tab + att * 65536 + k0;
            #pragma unroll
            for (int i = 0; i < 4; i++) {
                int c = l + 64 * i;
                int row = c >> 2, ko = (c & 3) << 3;
                int4 v = *(const int4*)(tb + (m0 + row) * 256 + ko);
                *(int4*)&As[att][row][ko] = v;
            }
        }
        // stage B: read Z (k-major complex), split, transpose to [j][k]
        #pragma unroll
        for (int pass = 0; pass < 4; pass++) {
            int j = 2 * bju + 16 * pass;
            float4 v = *(const float4*)(Zin + zbase + (size_t)(k0 + bk) * 128 + j * 2);
            short h0, l0, h1, l1;
            bsplit(v.x, h0, l0); bsplit(v.y, h1, l1);
            Bs[0][j][bk] = h0; Bs[1][j][bk] = l0; Bs[2][j][bk] = h1; Bs[3][j][bk] = l1;
            bsplit(v.z, h0, l0); bsplit(v.w, h1, l1);
            Bs[0][j + 1][bk] = h0; Bs[1][j + 1][bk] = l0; Bs[2][j + 1][bk] = h1; Bs[3][j + 1][bk] = l1;
        }
        __syncthreads();
        bf16x8 trh[2], trl[2], tih[2], til[2], zrh[2], zrl[2], zih[2], zil[2];
        #pragma unroll
        for (int s = 0; s < 2; s++) {
            int ar = wm * 32 + s * 16 + lr;
            trh[s] = *(const bf16x8*)&As[0][ar][lh << 3];
            trl[s] = *(const bf16x8*)&As[1][ar][lh << 3];
            tih[s] = *(const bf16x8*)&As[2][ar][lh << 3];
            til[s] = *(const bf16x8*)&As[3][ar][lh << 3];
            int br = wj * 32 + s * 16 + lr;
            zrh[s] = *(const bf16x8*)&Bs[0][br][lh << 3];
            zrl[s] = *(const bf16x8*)&Bs[1][br][lh << 3];
            zih[s] = *(const bf16x8*)&Bs[2][br][lh << 3];
            zil[s] = *(const bf16x8*)&Bs[3][br][lh << 3];
        }
        #pragma unroll
        for (int i = 0; i < 2; i++)
            #pragma unroll
            for (int jj = 0; jj < 2; jj++) {
                accRp[i][jj] = __builtin_amdgcn_mfma_f32_16x16x32_bf16(trh[i], zrh[jj], accRp[i][jj], 0, 0, 0);
                accRp[i][jj] = __builtin_amdgcn_mfma_f32_16x16x32_bf16(trh[i], zrl[jj], accRp[i][jj], 0, 0, 0);
                accRp[i][jj] = __builtin_amdgcn_mfma_f32_16x16x32_bf16(trl[i], zrh[jj], accRp[i][jj], 0, 0, 0);
                accRm[i][jj] = __builtin_amdgcn_mfma_f32_16x16x32_bf16(tih[i], zih[jj], accRm[i][jj], 0, 0, 0);
                accRm[i][jj] = __builtin_amdgcn_mfma_f32_16x16x32_bf16(tih[i], zil[jj], accRm[i][jj], 0, 0, 0);
                accRm[i][jj] = __builtin_amdgcn_mfma_f32_16x16x32_bf16(til[i], zih[jj], accRm[i][jj], 0, 0, 0);
                accI[i][jj]  = __builtin_amdgcn_mfma_f32_16x16x32_bf16(trh[i], zih[jj], accI[i][jj], 0, 0, 0);
                accI[i][jj]  = __builtin_amdgcn_mfma_f32_16x16x32_bf16(trh[i], zil[jj], accI[i][jj], 0, 0, 0);
                accI[i][jj]  = __builtin_amdgcn_mfma_f32_16x16x32_bf16(trl[i], zih[jj], accI[i][jj], 0, 0, 0);
                accI[i][jj]  = __builtin_amdgcn_mfma_f32_16x16x32_bf16(tih[i], zrh[jj], accI[i][jj], 0, 0, 0);
                accI[i][jj]  = __builtin_amdgcn_mfma_f32_16x16x32_bf16(tih[i], zrl[jj], accI[i][jj], 0, 0, 0);
                accI[i][jj]  = __builtin_amdgcn_mfma_f32_16x16x32_bf16(til[i], zrh[jj], accI[i][jj], 0, 0, 0);
            }
    }
    int b = p >> 6;
    #pragma unroll
    for (int i = 0; i < 2; i++)
        #pragma unroll
        for (int jj = 0; jj < 2; jj++) {
            int jcol = wj * 32 + jj * 16 + lr;
            #pragma unroll
            for (int r = 0; r < 4; r++) {
                int m = m0 + wm * 32 + i * 16 + (lh << 2) + r;
                float re = accRp[i][jj][r] - accRm[i][jj][r];
                float im = accI[i][jj][r];
                if (G) {
                    float2 g = ((const float2*)G)[((size_t)b * 256 + m) * 64 + jcol];
                    float nr = re * g.x - im * g.y;
                    float ni = re * g.y + im * g.x;
                    re = nr; im = ni;
                }
                ((float2*)(Zout + zbase))[(size_t)m * 64 + jcol] = make_float2(re, im);
            }
        }
}

// ---------------- E: out = x + Zc (rows x 128) * S (128 x 512), S on-the-fly ----------------
__global__ __launch_bounds__(256) void k_gemmE(const float* __restrict__ Zc,
                                               const float* __restrict__ x,
                                               float* __restrict__ out,
                                               int rowLo) {
    __shared__ __align__(16) float As[32][68];
    __shared__ __align__(16) float Bs[32][64];
    int t = threadIdx.x;
    int row0 = rowLo + blockIdx.x * 64, n0 = blockIdx.y * 64;
    int lr = t >> 3, lk4 = (t & 7) << 2;
    int bkr = t >> 4, bc4 = (t & 15) << 2;
    int ty = t >> 4, tx = t & 15;
    const float invN = 1.0f / 131072.0f;
    int par = bkr & 1;
    int wfh = bkr >> 1;
    float u_r[4], u_i[4], c8r[4], c8i[4], advr[4], advi[4];
    #pragma unroll
    for (int d = 0; d < 4; d++) {
        int w = n0 + bc4 + d;
        float s, c;
        sincosf((float)((w * wfh) & 511) * (TWOPI_F / 512.0f), &s, &c);
        u_r[d] = c; u_i[d] = -s;
        sincosf((float)((w * 8) & 511) * (TWOPI_F / 512.0f), &s, &c);
        c8r[d] = c; c8i[d] = -s;
        sincosf((float)((w * 16) & 511) * (TWOPI_F / 512.0f), &s, &c);
        advr[d] = c; advi[d] = -s;
    }
    float acc[4][4] = {};
    for (int k0 = 0; k0 < 128; k0 += 32) {
        __syncthreads();
        {
            float4 v = *(const float4*)(Zc + (size_t)(row0 + lr) * 128 + k0 + lk4);
            As[lk4 + 0][lr] = v.x; As[lk4 + 1][lr] = v.y;
            As[lk4 + 2][lr] = v.z; As[lk4 + 3][lr] = v.w;
        }
        {
            float4 v = *(const float4*)(Zc + (size_t)(row0 + lr + 32) * 128 + k0 + lk4);
            int mm = lr + 32;
            As[lk4 + 0][mm] = v.x; As[lk4 + 1][mm] = v.y;
            As[lk4 + 2][mm] = v.z; As[lk4 + 3][mm] = v.w;
        }
        int wf1 = (k0 >> 1) + wfh;
        float a1 = ((wf1 == 0) ? 1.0f : 2.0f) * invN;
        float a2 = 2.0f * invN;
        float b1[4], b2[4];
        #pragma unroll
        for (int d = 0; d < 4; d++) {
            b1[d] = a1 * (par ? u_i[d] : u_r[d]);
            float vr = u_r[d] * c8r[d] - u_i[d] * c8i[d];
            float vi = u_r[d] * c8i[d] + u_i[d] * c8r[d];
            b2[d] = a2 * (par ? vi : vr);
            float nr = u_r[d] * advr[d] - u_i[d] * advi[d];
            float ni = u_r[d] * advi[d] + u_i[d] * advr[d];
            u_r[d] = nr; u_i[d] = ni;
        }
        *(float4*)&Bs[bkr][bc4]      = make_float4(b1[0], b1[1], b1[2], b1[3]);
        *(float4*)&Bs[bkr + 16][bc4] = make_float4(b2[0], b2[1], b2[2], b2[3]);
        __syncthreads();
        #pragma unroll
        for (int kk = 0; kk < 32; kk++) {
            float4 ra = *(const float4*)&As[kk][ty << 2];
            float4 rb = *(const float4*)&Bs[kk][tx << 2];
            float a[4] = {ra.x, ra.y, ra.z, ra.w};
            float bq[4] = {rb.x, rb.y, rb.z, rb.w};
            #pragma unroll
            for (int i = 0; i < 4; i++)
                #pragma unroll
                for (int j = 0; j < 4; j++)
                    acc[i][j] = fmaf(a[i], bq[j], acc[i][j]);
        }
    }
    #pragma unroll
    for (int i = 0; i < 4; i++) {
        int r = row0 + (ty << 2) + i;
        size_t grow = (size_t)r * 512;
        float4 xv = *(const float4*)(x + grow + n0 + (tx << 2));
        *(float4*)(out + grow + n0 + (tx << 2)) =
            make_float4(acc[i][0] + xv.x, acc[i][1] + xv.y,
                        acc[i][2] + xv.z, acc[i][3] + xv.w);
    }
}

// ---------------- stage Zc planes 0..1 (65536 floats) into ws ----------------
__global__ __launch_bounds__(256) void k_copy(const float* __restrict__ src,
                                              float* __restrict__ dst) {
    int i = blockIdx.x * 256 + threadIdx.x;
    ((float4*)dst)[i] = ((const float4*)src)[i];
}

extern "C" void kernel_launch(void* const* d_in, const int* in_sizes, int n_in,
                              void* d_out, int out_size, void* d_ws, size_t ws_size,
                              hipStream_t stream) {
    (void)in_sizes; (void)n_in; (void)out_size; (void)ws_size;
    const float* x    = (const float*)d_in[0];
    const float* dt   = (const float*)d_in[1];
    const float* wmat = (const float*)d_in[2];
    const float* bvec = (const float*)d_in[3];
    float* out = (float*)d_out;
    float* ws  = (float*)d_ws;

    float* G   = out + G_OFF;     // [33.55M, 33.82M) floats of d_out
    float* Zw  = out;             // [0, 16.77M)
    float* Zh  = out + ZH_OFF;    // [16.77M, 33.55M)
    float* Zc  = out;             // reuses Zw region
    float* stg = ws;              // 65536 floats = 256 KB
    const short* tabF = (const short*)(out + TW_OFF);   // fwd tables (4 x 256 x 256 bf16)
    const short* tabI = tabF + 262144;                  // inv tables
    const short* tabA = (const short*)(out + TWA_OFF);  // gemmA W-DFT table (2 x 128 x 512 bf16)

    k_filt <<<2048,            256, 0, stream>>>(x, dt, wmat, bvec, G);
    k_twid <<<256,             256, 0, stream>>>(out);
    k_twidA<<<256,             256, 0, stream>>>(out);
    k_gemmA_mfma<<<2048,       256, 0, stream>>>(x, Zw, tabA);
    k_cgemm_mfma<<<dim3(512, 4), 256, 0, stream>>>(Zw, Zh, G, tabF);      // fwd h-DFT + filter
    k_cgemm_mfma<<<dim3(512, 4), 256, 0, stream>>>(Zh, Zc, nullptr, tabI); // inv h-DFT
    k_copy <<<64,              256, 0, stream>>>(Zc, stg);
    // Descending-plane cascade: out plane p clobbers Zc planes 4p..4p+3,
    // which are only read by strictly earlier launches.
    k_gemmE<<<dim3(1536, 8),   256, 0, stream>>>(Zc,  x, out, 128 * 256); // planes 128..511
    k_gemmE<<<dim3(384, 8),    256, 0, stream>>>(Zc,  x, out, 32 * 256);  // planes 32..127
    k_gemmE<<<dim3(96, 8),     256, 0, stream>>>(Zc,  x, out, 8 * 256);   // planes 8..31
    k_gemmE<<<dim3(24, 8),     256, 0, stream>>>(Zc,  x, out, 2 * 256);   // planes 2..7
    k_gemmE<<<dim3(8, 8),      256, 0, stream>>>(stg, x, out, 0);         // planes 0..1 (staged)
}